// Round 5
// baseline (2185.802 us; speedup 1.0000x reference)
//
#include <hip/hip_runtime.h>
#include <hip/hip_bf16.h>

typedef __hip_bfloat16 bf16;
typedef __bf16 bf16x8 __attribute__((ext_vector_type(8)));
typedef float f32x4 __attribute__((ext_vector_type(4)));

// ---------------- sizes ----------------
// B=2, T=2048, D=1024, H=16, HD=64; BT = 4096 rows. ALL inputs f32; output f32.
static constexpr size_t MB = 1ull << 20;

// ws layout (bytes) — total < 64 MiB, aggressive aliasing:
static constexpr size_t OFF_XXXQ = 0;                 // bf16 4096x1024 (8 MiB): xxx, then q
static constexpr size_t OFF_MP   = 8 * MB;            // f32  4096x256  (4 MiB)
static constexpr size_t OFF_XSAG = 12 * MB;           // bf16 4096x1024 (8 MiB): per-stream xs, then o*gate
static constexpr size_t OFF_DECT = 20 * MB;           // bf16 4096x128  (1 MiB)
static constexpr size_t OFF_W    = 21 * MB;           // bf16 4096x1024 (8 MiB)  w = exp(decay)
static constexpr size_t OFF_K    = 29 * MB;           // bf16 4096x1024 (8 MiB)
static constexpr size_t OFF_V    = 37 * MB;           // bf16 4096x1024 (8 MiB)
static constexpr size_t OFF_GATE = 45 * MB;           // bf16 4096x1024 (8 MiB)
static constexpr size_t OFF_WQT  = 53 * MB;           // bf16 1024x1024 (2 MiB) x5
static constexpr size_t OFF_WKT  = 55 * MB;
static constexpr size_t OFF_WVT  = 57 * MB;
static constexpr size_t OFF_WGT  = 59 * MB;
static constexpr size_t OFF_WOT  = 61 * MB;
static constexpr size_t OFF_W1T  = 63 * MB;                 // bf16 256x1024 (0.5 MiB)
static constexpr size_t OFF_WD1T = 63 * MB + 512 * 1024;    // bf16 128x1024 (0.25 MiB)
static constexpr size_t OFF_WD2T = 63 * MB + 768 * 1024;    // bf16 1024x64  (128 KiB)

// ---------------- async 16B global->LDS ----------------
__device__ __forceinline__ void async_ld16(const void* g, void* l) {
    __builtin_amdgcn_global_load_lds((const __attribute__((address_space(1))) void*)g,
                                     (__attribute__((address_space(3))) void*)l, 16, 0, 0);
}

// ---------------- transpose f32 -> bf16 with column padding: dst[c][r] = (c<C)? src[r][c] : 0 ----
__global__ void transpose_pad(const float* __restrict__ src, bf16* __restrict__ dst,
                              int R, int C, int Cpad) {
    __shared__ bf16 tile[32][33];
    int r0 = blockIdx.x * 32, c0 = blockIdx.y * 32;
    int tx = threadIdx.x, ty = threadIdx.y;  // block (32,8)
#pragma unroll
    for (int yy = 0; yy < 4; ++yy) {
        int r = r0 + ty + yy * 8, c = c0 + tx;
        float v = (r < R && c < C) ? src[(size_t)r * C + c] : 0.f;
        tile[ty + yy * 8][tx] = __float2bfloat16(v);
    }
    __syncthreads();
#pragma unroll
    for (int yy = 0; yy < 4; ++yy) {
        int c = c0 + ty + yy * 8, r = r0 + tx;
        if (c < Cpad && r < R) dst[(size_t)c * R + r] = tile[tx][ty + yy * 8];
    }
}

// ---------------- xxx = x + dxprev * maa_x ----------------
__global__ void prep_xxx(const float* __restrict__ x, const float* __restrict__ maa_x,
                         bf16* __restrict__ xxx) {
    int i = blockIdx.x * 256 + threadIdx.x;      // 0..4M-1
    int d = i & 1023;
    int t = (i >> 10) & 2047;
    float xv = x[i];
    float xp = (t > 0) ? x[i - 1024] : 0.f;
    xxx[i] = __float2bfloat16(xv + (xp - xv) * maa_x[d]);
}

// ---------------- m97-style bf16 MFMA GEMM: C(M,N) = A(M,K) @ Bt(N,K)^T ----------------
// EPI: 1 = f32 tanh; 2 = bf16 tanh; 3 = bf16 w=exp(aux+v); 4 = bf16 silu(v+aux);
//      5 = bf16 plain; 6 = f32 plain
template<int EPI>
__global__ __launch_bounds__(256)
void gemm_bt(const bf16* __restrict__ A, int lda,
             const bf16* __restrict__ Bt, int ldb,
             void* __restrict__ Cout, int ldc,
             int K, const float* __restrict__ aux)
{
    __shared__ __align__(16) bf16 As[128 * 32];
    __shared__ __align__(16) bf16 Bs[128 * 32];
    const int m0 = blockIdx.x * 128;
    const int n0 = blockIdx.y * 128;
    const int tid = threadIdx.x;
    const int lane = tid & 63;
    const int w = tid >> 6;
    const int wm = w >> 1, wn = w & 1;
    const int row16 = lane & 15;
    const int quad = lane >> 4;

    f32x4 acc[4][4];
#pragma unroll
    for (int mi = 0; mi < 4; ++mi)
#pragma unroll
        for (int ni = 0; ni < 4; ++ni)
            acc[mi][ni] = (f32x4){0.f, 0.f, 0.f, 0.f};

    for (int k0 = 0; k0 < K; k0 += 32) {
        __syncthreads();   // previous iter's LDS reads complete
#pragma unroll
        for (int j = 0; j < 2; ++j) {
            int i = j * 256 + w * 64 + lane;
            int ri = i >> 2;
            int ci = (i & 3) * 8;
            const bf16* ga = A  + (size_t)(m0 + ri) * lda + (k0 + ci);
            const bf16* gb = Bt + (size_t)(n0 + ri) * ldb + (k0 + ci);
            bf16* la = As + (size_t)(j * 256 + w * 64) * 8;   // wave-uniform base
            bf16* lb = Bs + (size_t)(j * 256 + w * 64) * 8;
            async_ld16(ga, la);
            async_ld16(gb, lb);
        }
        __syncthreads();   // staging drained (vmcnt(0) before barrier)
        bf16x8 af[4], bfr[4];
#pragma unroll
        for (int mi = 0; mi < 4; ++mi)
            af[mi] = *(const bf16x8*)(As + ((wm * 64 + mi * 16 + row16) * 32 + quad * 8));
#pragma unroll
        for (int ni = 0; ni < 4; ++ni)
            bfr[ni] = *(const bf16x8*)(Bs + ((wn * 64 + ni * 16 + row16) * 32 + quad * 8));
#pragma unroll
        for (int mi = 0; mi < 4; ++mi)
#pragma unroll
            for (int ni = 0; ni < 4; ++ni)
                acc[mi][ni] = __builtin_amdgcn_mfma_f32_16x16x32_bf16(af[mi], bfr[ni], acc[mi][ni], 0, 0, 0);
    }
    // epilogue: C/D layout col=lane&15, row=quad*4+reg (m89/m91-verified)
#pragma unroll
    for (int mi = 0; mi < 4; ++mi)
#pragma unroll
        for (int ni = 0; ni < 4; ++ni)
#pragma unroll
            for (int r = 0; r < 4; ++r) {
                int gr = m0 + wm * 64 + mi * 16 + quad * 4 + r;
                int gc = n0 + wn * 64 + ni * 16 + row16;
                size_t ci = (size_t)gr * ldc + gc;
                float v = acc[mi][ni][r];
                if (EPI == 1) ((float*)Cout)[ci] = tanhf(v);
                else if (EPI == 2) ((bf16*)Cout)[ci] = __float2bfloat16(tanhf(v));
                else if (EPI == 3) {
                    // w = exp(decay); store pre-outer-exp for bf16 precision
                    float t = aux[gc] + v;
                    ((bf16*)Cout)[ci] = __float2bfloat16(expf(t));
                } else if (EPI == 4) {
                    float z = v + aux[gc];
                    ((bf16*)Cout)[ci] = __float2bfloat16(z / (1.f + expf(-z)));  // silu
                } else if (EPI == 5) {
                    ((bf16*)Cout)[ci] = __float2bfloat16(v);
                } else {
                    ((float*)Cout)[ci] = v;   // EPI 6: f32 plain (final output)
                }
            }
}

// ---------------- one stream: xs = x + dxprev * (maa_f + mp_f @ w2_f) ----------------
__global__ __launch_bounds__(256)
void mix_stream(const float* __restrict__ mp,    // (4096,256) f32, cols [f*32, f*32+32) used
                const float* __restrict__ w2,    // (5,32,1024)
                const float* __restrict__ x,
                const float* __restrict__ maa_f,
                int f,
                bf16* __restrict__ xs)
{
    __shared__ float mps[4][32];
    int dg = blockIdx.x;          // 0..3
    int r0 = blockIdx.y * 4;      // 4 rows per block
    int tid = threadIdx.x;
    int d = dg * 256 + tid;
    if (tid < 128) {
        int rr = tid >> 5, l = tid & 31;
        mps[rr][l] = mp[(size_t)(r0 + rr) * 256 + f * 32 + l];
    }
    __syncthreads();
    float acc[4] = {0.f, 0.f, 0.f, 0.f};
#pragma unroll
    for (int l = 0; l < 32; ++l) {
        float wv = w2[(size_t)(f * 32 + l) * 1024 + d];
#pragma unroll
        for (int rr = 0; rr < 4; ++rr)
            acc[rr] = fmaf(mps[rr][l], wv, acc[rr]);
    }
    float mf = maa_f[d];
#pragma unroll
    for (int rr = 0; rr < 4; ++rr) {
        int r = r0 + rr;
        int t = r & 2047;
        size_t i = (size_t)r * 1024 + d;
        float xv = x[i];
        float xp = (t > 0) ? x[i - 1024] : 0.f;
        xs[i] = __float2bfloat16(xv + (xp - xv) * (mf + acc[rr]));
    }
}

// ---------------- sequential gated linear attention scan, gate fused ----------------
// one block (64 threads = 1 wave) per (b,h); lane = v-column; S[k][lane] in regs
__global__ __launch_bounds__(64)
void recur_kernel(const bf16* __restrict__ q, const bf16* __restrict__ k,
                  const bf16* __restrict__ v, const bf16* __restrict__ w,
                  const bf16* __restrict__ gate, bf16* __restrict__ ag)
{
    int bh = blockIdx.x;             // 0..31
    int b = bh >> 4, h = bh & 15;
    int lane = threadIdx.x;
    __shared__ __align__(16) float sh[2][3][64];
    size_t base = (size_t)b * 2048 * 1024 + (size_t)h * 64;

    float S[64];
#pragma unroll
    for (int i = 0; i < 64; ++i) S[i] = 0.f;

    size_t idx = base + lane;
    float ql = __bfloat162float(q[idx]) * 0.125f;   // HD^-0.5
    float kl = __bfloat162float(k[idx]);
    float wl = __bfloat162float(w[idx]);
    float vl = __bfloat162float(v[idx]);
    float gl = __bfloat162float(gate[idx]);

    for (int t = 0; t < 2048; ++t) {
        int p = t & 1;
        float el = __expf(-wl);             // eg = exp(g_log), g_log = -w
        sh[p][0][lane] = ql;
        sh[p][1][lane] = kl * (1.f - el);   // bonus: k * (1 - exp(g_log))
        sh[p][2][lane] = el;
        float vcur = vl;
        float gcur = gl;
        if (t + 1 < 2048) {
            size_t ni = base + (size_t)(t + 1) * 1024 + lane;
            ql = __bfloat162float(q[ni]) * 0.125f;
            kl = __bfloat162float(k[ni]);
            wl = __bfloat162float(w[ni]);
            vl = __bfloat162float(v[ni]);
            gl = __bfloat162float(gate[ni]);
        }
        __syncthreads();
        const float4* q4 = (const float4*)sh[p][0];
        const float4* k4 = (const float4*)sh[p][1];
        const float4* e4 = (const float4*)sh[p][2];
        float a0 = 0.f, a1 = 0.f, a2 = 0.f, a3 = 0.f;
#pragma unroll
        for (int kk = 0; kk < 16; ++kk) {
            float4 qq = q4[kk], kx = k4[kk], ee = e4[kk];
            int s = kk * 4;
            S[s + 0] = S[s + 0] * ee.x + kx.x * vcur; a0 += qq.x * S[s + 0];
            S[s + 1] = S[s + 1] * ee.y + kx.y * vcur; a1 += qq.y * S[s + 1];
            S[s + 2] = S[s + 2] * ee.z + kx.z * vcur; a2 += qq.z * S[s + 2];
            S[s + 3] = S[s + 3] * ee.w + kx.w * vcur; a3 += qq.w * S[s + 3];
        }
        ag[base + (size_t)t * 1024 + lane] = __float2bfloat16(((a0 + a1) + (a2 + a3)) * gcur);
    }
}

// ---------------- launch ----------------
extern "C" void kernel_launch(void* const* d_in, const int* in_sizes, int n_in,
                              void* d_out, int out_size, void* d_ws, size_t ws_size,
                              hipStream_t stream) {
    const float* x    = (const float*)d_in[0];
    const float* maax = (const float*)d_in[1];
    const float* maar = (const float*)d_in[2];
    const float* maak = (const float*)d_in[3];
    const float* maav = (const float*)d_in[4];
    const float* maaw = (const float*)d_in[5];
    const float* maag = (const float*)d_in[6];
    const float* w1   = (const float*)d_in[7];   // (1024,160)
    const float* w2   = (const float*)d_in[8];   // (5,32,1024)  order r,k,v,w,g
    const float* td   = (const float*)d_in[9];   // (1024)
    const float* dw1  = (const float*)d_in[10];  // (1024,64)
    const float* dw2  = (const float*)d_in[11];  // (64,1024)
    const float* Wq   = (const float*)d_in[12];
    const float* Wk   = (const float*)d_in[13];
    const float* Wv   = (const float*)d_in[14];
    const float* Wo   = (const float*)d_in[15];
    const float* Wg   = (const float*)d_in[16];
    const float* bg   = (const float*)d_in[17];

    char* ws = (char*)d_ws;
    bf16*  xxx   = (bf16*) (ws + OFF_XXXQ);
    bf16*  qb    = (bf16*) (ws + OFF_XXXQ);   // reuse: xxx dead after mp gemm
    float* mp    = (float*)(ws + OFF_MP);
    bf16*  xs    = (bf16*) (ws + OFF_XSAG);   // per-stream buffer, reused 5x
    bf16*  ag    = (bf16*) (ws + OFF_XSAG);   // reuse: xs dead after gate gemm
    bf16*  dect  = (bf16*) (ws + OFF_DECT);
    bf16*  wb    = (bf16*) (ws + OFF_W);
    bf16*  kb    = (bf16*) (ws + OFF_K);
    bf16*  vb    = (bf16*) (ws + OFF_V);
    bf16*  gateb = (bf16*) (ws + OFF_GATE);
    bf16*  wqt   = (bf16*) (ws + OFF_WQT);
    bf16*  wkt   = (bf16*) (ws + OFF_WKT);
    bf16*  wvt   = (bf16*) (ws + OFF_WVT);
    bf16*  wgt   = (bf16*) (ws + OFF_WGT);
    bf16*  wot   = (bf16*) (ws + OFF_WOT);
    bf16*  w1t   = (bf16*) (ws + OFF_W1T);
    bf16*  wd1t  = (bf16*) (ws + OFF_WD1T);
    bf16*  wd2t  = (bf16*) (ws + OFF_WD2T);

    dim3 tb(32, 8);
    transpose_pad<<<dim3(32, 32), tb, 0, stream>>>(Wq,  wqt, 1024, 1024, 1024);
    transpose_pad<<<dim3(32, 32), tb, 0, stream>>>(Wk,  wkt, 1024, 1024, 1024);
    transpose_pad<<<dim3(32, 32), tb, 0, stream>>>(Wv,  wvt, 1024, 1024, 1024);
    transpose_pad<<<dim3(32, 32), tb, 0, stream>>>(Wg,  wgt, 1024, 1024, 1024);
    transpose_pad<<<dim3(32, 32), tb, 0, stream>>>(Wo,  wot, 1024, 1024, 1024);
    transpose_pad<<<dim3(32,  8), tb, 0, stream>>>(w1,  w1t, 1024, 160,  256);
    transpose_pad<<<dim3(32,  4), tb, 0, stream>>>(dw1, wd1t, 1024, 64,  128);
    transpose_pad<<<dim3(2,  32), tb, 0, stream>>>(dw2, wd2t, 64,  1024, 1024);

    prep_xxx<<<16384, 256, 0, stream>>>(x, maax, xxx);

    // mp = tanh(xxx @ W1)   (4096,256 padded, f32)
    gemm_bt<1><<<dim3(32, 2), 256, 0, stream>>>(xxx, 1024, w1t, 1024, mp, 256, 1024, nullptr);

    // ---- stream w (f=3): decay chain -> wb = exp(decay) ----
    mix_stream<<<dim3(4, 1024), 256, 0, stream>>>(mp, w2, x, maaw, 3, xs);
    gemm_bt<2><<<dim3(32, 1), 256, 0, stream>>>(xs, 1024, wd1t, 1024, dect, 128, 1024, nullptr);
    gemm_bt<3><<<dim3(32, 8), 256, 0, stream>>>(dect, 128, wd2t, 64, wb, 1024, 64, td);

    // ---- stream r (f=0): q ----
    mix_stream<<<dim3(4, 1024), 256, 0, stream>>>(mp, w2, x, maar, 0, xs);
    gemm_bt<5><<<dim3(32, 8), 256, 0, stream>>>(xs, 1024, wqt, 1024, qb, 1024, 1024, nullptr);

    // ---- stream k (f=1) ----
    mix_stream<<<dim3(4, 1024), 256, 0, stream>>>(mp, w2, x, maak, 1, xs);
    gemm_bt<5><<<dim3(32, 8), 256, 0, stream>>>(xs, 1024, wkt, 1024, kb, 1024, 1024, nullptr);

    // ---- stream v (f=2) ----
    mix_stream<<<dim3(4, 1024), 256, 0, stream>>>(mp, w2, x, maav, 2, xs);
    gemm_bt<5><<<dim3(32, 8), 256, 0, stream>>>(xs, 1024, wvt, 1024, vb, 1024, 1024, nullptr);

    // ---- stream g (f=4): gate = silu(xg @ Wg + bg) ----
    mix_stream<<<dim3(4, 1024), 256, 0, stream>>>(mp, w2, x, maag, 4, xs);
    gemm_bt<4><<<dim3(32, 8), 256, 0, stream>>>(xs, 1024, wgt, 1024, gateb, 1024, 1024, bg);

    // ---- scan (gate fused) -> ag = o * gate (bf16, reuses xs region) ----
    recur_kernel<<<32, 64, 0, stream>>>(qb, kb, vb, wb, gateb, ag);

    // out = ag @ Wo  -> f32 (reference output dtype)
    gemm_bt<6><<<dim3(32, 8), 256, 0, stream>>>(ag, 1024, wot, 1024, (float*)d_out, 1024, 1024, nullptr);

    (void)in_sizes; (void)n_in; (void)out_size; (void)ws_size;
}

// Round 6
// 682.054 us; speedup vs baseline: 3.2047x; 3.2047x over previous
//
#include <hip/hip_runtime.h>
#include <hip/hip_bf16.h>

typedef __hip_bfloat16 bf16;
typedef __bf16 bf16x8 __attribute__((ext_vector_type(8)));
typedef float f32x4 __attribute__((ext_vector_type(4)));

// ---------------- sizes ----------------
// B=2, T=2048, D=1024, H=16, HD=64; BT = 4096 rows. ALL inputs f32; output f32.
// Scan chunking: NC=16 chunks of L=128 per (b,h).
static constexpr size_t MB = 1ull << 20;

// ws layout (bytes) — total < 64 MiB, aggressive aliasing:
static constexpr size_t OFF_XXXQ = 0;                 // bf16 4096x1024 (8 MiB): xxx, then q
static constexpr size_t OFF_MP   = 8 * MB;            // f32  4096x256  (4 MiB)
static constexpr size_t OFF_XSAG = 12 * MB;           // bf16 4096x1024 (8 MiB): per-stream xs, then o*gate
static constexpr size_t OFF_DECT = 20 * MB;           // bf16 4096x128 (1 MiB): dect, then D (f32 32x16x64)
static constexpr size_t OFF_W    = 21 * MB;           // bf16 4096x1024 (8 MiB)  w = exp(decay)
static constexpr size_t OFF_K    = 29 * MB;           // bf16 4096x1024 (8 MiB)
static constexpr size_t OFF_V    = 37 * MB;           // bf16 4096x1024 (8 MiB)
static constexpr size_t OFF_GATE = 45 * MB;           // bf16 4096x1024 (8 MiB)
static constexpr size_t OFF_WQT  = 53 * MB;           // bf16 1024x1024 (2 MiB) x4 (wqt,wkt,wvt,wgt)
static constexpr size_t OFF_WKT  = 55 * MB;           //   -> dead before scan; reused as Sloc/S0
static constexpr size_t OFF_WVT  = 57 * MB;           //      f32 [32][16][64][64] = 8 MiB
static constexpr size_t OFF_WGT  = 59 * MB;
static constexpr size_t OFF_WOT  = 61 * MB;           // bf16 1024x1024 (live until final gemm)
static constexpr size_t OFF_W1T  = 63 * MB;                 // bf16 256x1024 (0.5 MiB)
static constexpr size_t OFF_WD1T = 63 * MB + 512 * 1024;    // bf16 128x1024 (0.25 MiB)
static constexpr size_t OFF_WD2T = 63 * MB + 768 * 1024;    // bf16 1024x64  (128 KiB)
static constexpr size_t OFF_SLOC = OFF_WQT;           // f32 8 MiB, [bh][c][v][k]
static constexpr size_t OFF_D    = OFF_DECT;          // f32 128 KiB, [bh][c][k]

// ---------------- helpers ----------------
__device__ __forceinline__ void async_ld16(const void* g, void* l) {
    __builtin_amdgcn_global_load_lds((const __attribute__((address_space(1))) void*)g,
                                     (__attribute__((address_space(3))) void*)l, 16, 0, 0);
}
__device__ __forceinline__ float bf2f(unsigned short u) {
    union { unsigned int i; float f; } x; x.i = ((unsigned int)u) << 16; return x.f;
}

// ---------------- transpose f32 -> bf16 with column padding ----------------
__global__ void transpose_pad(const float* __restrict__ src, bf16* __restrict__ dst,
                              int R, int C, int Cpad) {
    __shared__ bf16 tile[32][33];
    int r0 = blockIdx.x * 32, c0 = blockIdx.y * 32;
    int tx = threadIdx.x, ty = threadIdx.y;  // block (32,8)
#pragma unroll
    for (int yy = 0; yy < 4; ++yy) {
        int r = r0 + ty + yy * 8, c = c0 + tx;
        float v = (r < R && c < C) ? src[(size_t)r * C + c] : 0.f;
        tile[ty + yy * 8][tx] = __float2bfloat16(v);
    }
    __syncthreads();
#pragma unroll
    for (int yy = 0; yy < 4; ++yy) {
        int c = c0 + ty + yy * 8, r = r0 + tx;
        if (c < Cpad && r < R) dst[(size_t)c * R + r] = tile[tx][ty + yy * 8];
    }
}

// ---------------- xxx = x + dxprev * maa_x ----------------
__global__ void prep_xxx(const float* __restrict__ x, const float* __restrict__ maa_x,
                         bf16* __restrict__ xxx) {
    int i = blockIdx.x * 256 + threadIdx.x;      // 0..4M-1
    int d = i & 1023;
    int t = (i >> 10) & 2047;
    float xv = x[i];
    float xp = (t > 0) ? x[i - 1024] : 0.f;
    xxx[i] = __float2bfloat16(xv + (xp - xv) * maa_x[d]);
}

// ---------------- m97-style bf16 MFMA GEMM: C(M,N) = A(M,K) @ Bt(N,K)^T ----------------
// EPI: 1 = f32 tanh; 2 = bf16 tanh; 3 = bf16 w=exp(aux+v); 4 = bf16 silu(v+aux);
//      5 = bf16 plain; 6 = f32 plain
template<int EPI>
__global__ __launch_bounds__(256)
void gemm_bt(const bf16* __restrict__ A, int lda,
             const bf16* __restrict__ Bt, int ldb,
             void* __restrict__ Cout, int ldc,
             int K, const float* __restrict__ aux)
{
    __shared__ __align__(16) bf16 As[128 * 32];
    __shared__ __align__(16) bf16 Bs[128 * 32];
    const int m0 = blockIdx.x * 128;
    const int n0 = blockIdx.y * 128;
    const int tid = threadIdx.x;
    const int lane = tid & 63;
    const int w = tid >> 6;
    const int wm = w >> 1, wn = w & 1;
    const int row16 = lane & 15;
    const int quad = lane >> 4;

    f32x4 acc[4][4];
#pragma unroll
    for (int mi = 0; mi < 4; ++mi)
#pragma unroll
        for (int ni = 0; ni < 4; ++ni)
            acc[mi][ni] = (f32x4){0.f, 0.f, 0.f, 0.f};

    for (int k0 = 0; k0 < K; k0 += 32) {
        __syncthreads();
#pragma unroll
        for (int j = 0; j < 2; ++j) {
            int i = j * 256 + w * 64 + lane;
            int ri = i >> 2;
            int ci = (i & 3) * 8;
            const bf16* ga = A  + (size_t)(m0 + ri) * lda + (k0 + ci);
            const bf16* gb = Bt + (size_t)(n0 + ri) * ldb + (k0 + ci);
            bf16* la = As + (size_t)(j * 256 + w * 64) * 8;
            bf16* lb = Bs + (size_t)(j * 256 + w * 64) * 8;
            async_ld16(ga, la);
            async_ld16(gb, lb);
        }
        __syncthreads();
        bf16x8 af[4], bfr[4];
#pragma unroll
        for (int mi = 0; mi < 4; ++mi)
            af[mi] = *(const bf16x8*)(As + ((wm * 64 + mi * 16 + row16) * 32 + quad * 8));
#pragma unroll
        for (int ni = 0; ni < 4; ++ni)
            bfr[ni] = *(const bf16x8*)(Bs + ((wn * 64 + ni * 16 + row16) * 32 + quad * 8));
#pragma unroll
        for (int mi = 0; mi < 4; ++mi)
#pragma unroll
            for (int ni = 0; ni < 4; ++ni)
                acc[mi][ni] = __builtin_amdgcn_mfma_f32_16x16x32_bf16(af[mi], bfr[ni], acc[mi][ni], 0, 0, 0);
    }
#pragma unroll
    for (int mi = 0; mi < 4; ++mi)
#pragma unroll
        for (int ni = 0; ni < 4; ++ni)
#pragma unroll
            for (int r = 0; r < 4; ++r) {
                int gr = m0 + wm * 64 + mi * 16 + quad * 4 + r;
                int gc = n0 + wn * 64 + ni * 16 + row16;
                size_t ci = (size_t)gr * ldc + gc;
                float v = acc[mi][ni][r];
                if (EPI == 1) ((float*)Cout)[ci] = tanhf(v);
                else if (EPI == 2) ((bf16*)Cout)[ci] = __float2bfloat16(tanhf(v));
                else if (EPI == 3) {
                    float t = aux[gc] + v;
                    ((bf16*)Cout)[ci] = __float2bfloat16(expf(t));   // w = exp(decay)
                } else if (EPI == 4) {
                    float z = v + aux[gc];
                    ((bf16*)Cout)[ci] = __float2bfloat16(z / (1.f + expf(-z)));  // silu
                } else if (EPI == 5) {
                    ((bf16*)Cout)[ci] = __float2bfloat16(v);
                } else {
                    ((float*)Cout)[ci] = v;   // EPI 6: f32 plain (final output)
                }
            }
}

// ---------------- one stream: xs = x + dxprev * (maa_f + mp_f @ w2_f) ----------------
__global__ __launch_bounds__(256)
void mix_stream(const float* __restrict__ mp,    // (4096,256) f32, cols [f*32,f*32+32)
                const float* __restrict__ w2,    // (5,32,1024)
                const float* __restrict__ x,
                const float* __restrict__ maa_f,
                int f,
                bf16* __restrict__ xs)
{
    __shared__ float mps[4][32];
    int dg = blockIdx.x;          // 0..3
    int r0 = blockIdx.y * 4;      // 4 rows per block
    int tid = threadIdx.x;
    int d = dg * 256 + tid;
    if (tid < 128) {
        int rr = tid >> 5, l = tid & 31;
        mps[rr][l] = mp[(size_t)(r0 + rr) * 256 + f * 32 + l];
    }
    __syncthreads();
    float acc[4] = {0.f, 0.f, 0.f, 0.f};
#pragma unroll
    for (int l = 0; l < 32; ++l) {
        float wv = w2[(size_t)(f * 32 + l) * 1024 + d];
#pragma unroll
        for (int rr = 0; rr < 4; ++rr)
            acc[rr] = fmaf(mps[rr][l], wv, acc[rr]);
    }
    float mf = maa_f[d];
#pragma unroll
    for (int rr = 0; rr < 4; ++rr) {
        int r = r0 + rr;
        int t = r & 2047;
        size_t i = (size_t)r * 1024 + d;
        float xv = x[i];
        float xp = (t > 0) ? x[i - 1024] : 0.f;
        xs[i] = __float2bfloat16(xv + (xp - xv) * (mf + acc[rr]));
    }
}

// ================= chunked gated-linear-attention scan =================
// Phase A: per (bh, chunk c): local state Sloc[v][k] (zero-init recurrence over
// L=128 steps, no outputs) and per-k decay product D[k]. lane = k.
__global__ __launch_bounds__(64)
void chunk_state(const bf16* __restrict__ k, const bf16* __restrict__ v,
                 const bf16* __restrict__ w,
                 float* __restrict__ Sloc, float* __restrict__ D)
{
    int c = blockIdx.x, bh = blockIdx.y;
    int b = bh >> 4, h = bh & 15;
    int lane = threadIdx.x;            // k index
    __shared__ __align__(16) float sh[2][64];   // v broadcast
    size_t base = (size_t)b * 2048 * 1024 + (size_t)h * 64 + (size_t)c * 128 * 1024;

    float S[64];                       // S[v] for k = lane
#pragma unroll
    for (int i = 0; i < 64; ++i) S[i] = 0.f;
    float Dl = 1.f;

    const unsigned short* kp = (const unsigned short*)k;
    const unsigned short* vp = (const unsigned short*)v;
    const unsigned short* wp = (const unsigned short*)w;
    unsigned short kr[4], vr[4], wr[4];
#pragma unroll
    for (int j = 0; j < 4; ++j) {
        size_t a = base + (size_t)j * 1024 + lane;
        kr[j] = kp[a]; vr[j] = vp[a]; wr[j] = wp[a];
    }
    for (int t = 0; t < 128; ++t) {
        int slot = t & 3, p = t & 1;
        float kl = bf2f(kr[slot]);
        float vl = bf2f(vr[slot]);
        float wl = bf2f(wr[slot]);
        if (t + 4 < 128) {
            size_t a = base + (size_t)(t + 4) * 1024 + lane;
            kr[slot] = kp[a]; vr[slot] = vp[a]; wr[slot] = wp[a];
        }
        float el = __expf(-wl);        // decay for k=lane
        float kb = kl * (1.f - el);    // k bonus
        Dl *= el;
        sh[p][lane] = vl;
        __syncthreads();
        const float4* v4 = (const float4*)sh[p];
#pragma unroll
        for (int vv = 0; vv < 16; ++vv) {
            float4 vx = v4[vv];
            int s = vv * 4;
            S[s + 0] = S[s + 0] * el + kb * vx.x;
            S[s + 1] = S[s + 1] * el + kb * vx.y;
            S[s + 2] = S[s + 2] * el + kb * vx.z;
            S[s + 3] = S[s + 3] * el + kb * vx.w;
        }
    }
    // store [bh][c][v][k]: lane-coalesced over k
    float* So = Sloc + ((size_t)bh * 16 + c) * 4096;
#pragma unroll
    for (int i = 0; i < 64; ++i) So[(size_t)i * 64 + lane] = S[i];
    D[((size_t)bh * 16 + c) * 64 + lane] = Dl;
}

// Phase B: sequential combine over chunks (exact): S0_{c+1} = S0_c*D_c + Sloc_c.
// Overwrites Sloc_c with S0_c (state at chunk start). Parallel over (v,k).
__global__ __launch_bounds__(256)
void chunk_combine(float* __restrict__ Sloc, const float* __restrict__ D)
{
    int bh = blockIdx.x;
    int tid = threadIdx.x;
    int k = tid & 63, v0 = tid >> 6;
#pragma unroll
    for (int j = 0; j < 16; ++j) {
        int v = v0 + j * 4;
        float s = 0.f;
        for (int c = 0; c < 16; ++c) {
            size_t idx = ((size_t)bh * 16 + c) * 4096 + (size_t)v * 64 + k;
            float tmp = Sloc[idx];
            Sloc[idx] = s;
            s = s * D[((size_t)bh * 16 + c) * 64 + k] + tmp;
        }
    }
}

// Phase C: per (bh, chunk): run recurrence from S0_c producing outputs, gate fused.
// lane = v; S[k] in regs; 4-deep register ring prefetch on 5 input streams.
__global__ __launch_bounds__(64)
void chunk_out(const bf16* __restrict__ q, const bf16* __restrict__ k,
               const bf16* __restrict__ v, const bf16* __restrict__ w,
               const bf16* __restrict__ gate, const float* __restrict__ S0buf,
               bf16* __restrict__ ag)
{
    int c = blockIdx.x, bh = blockIdx.y;
    int b = bh >> 4, h = bh & 15;
    int lane = threadIdx.x;            // v index
    __shared__ __align__(16) float sh[2][3][64];
    size_t base = (size_t)b * 2048 * 1024 + (size_t)h * 64 + (size_t)c * 128 * 1024;

    // init S[k] = S0[v=lane][k]
    float S[64];
    const float4* S0 = (const float4*)(S0buf + ((size_t)bh * 16 + c) * 4096 + (size_t)lane * 64);
#pragma unroll
    for (int i = 0; i < 16; ++i) {
        float4 x4 = S0[i];
        S[i * 4 + 0] = x4.x; S[i * 4 + 1] = x4.y; S[i * 4 + 2] = x4.z; S[i * 4 + 3] = x4.w;
    }

    const unsigned short* qp = (const unsigned short*)q;
    const unsigned short* kp = (const unsigned short*)k;
    const unsigned short* vp = (const unsigned short*)v;
    const unsigned short* wp = (const unsigned short*)w;
    const unsigned short* gp = (const unsigned short*)gate;
    unsigned short qr[4], kr[4], vr[4], wr[4], gr[4];
#pragma unroll
    for (int j = 0; j < 4; ++j) {
        size_t a = base + (size_t)j * 1024 + lane;
        qr[j] = qp[a]; kr[j] = kp[a]; vr[j] = vp[a]; wr[j] = wp[a]; gr[j] = gp[a];
    }
    for (int t = 0; t < 128; ++t) {
        int slot = t & 3, p = t & 1;
        float ql = bf2f(qr[slot]) * 0.125f;   // HD^-0.5
        float kl = bf2f(kr[slot]);
        float vl = bf2f(vr[slot]);
        float wl = bf2f(wr[slot]);
        float gl = bf2f(gr[slot]);
        if (t + 4 < 128) {
            size_t a = base + (size_t)(t + 4) * 1024 + lane;
            qr[slot] = qp[a]; kr[slot] = kp[a]; vr[slot] = vp[a];
            wr[slot] = wp[a]; gr[slot] = gp[a];
        }
        float el = __expf(-wl);
        sh[p][0][lane] = ql;
        sh[p][1][lane] = kl * (1.f - el);
        sh[p][2][lane] = el;
        __syncthreads();
        const float4* q4 = (const float4*)sh[p][0];
        const float4* k4 = (const float4*)sh[p][1];
        const float4* e4 = (const float4*)sh[p][2];
        float a0 = 0.f, a1 = 0.f, a2 = 0.f, a3 = 0.f;
#pragma unroll
        for (int kk = 0; kk < 16; ++kk) {
            float4 qq = q4[kk], kx = k4[kk], ee = e4[kk];
            int s = kk * 4;
            S[s + 0] = S[s + 0] * ee.x + kx.x * vl; a0 += qq.x * S[s + 0];
            S[s + 1] = S[s + 1] * ee.y + kx.y * vl; a1 += qq.y * S[s + 1];
            S[s + 2] = S[s + 2] * ee.z + kx.z * vl; a2 += qq.z * S[s + 2];
            S[s + 3] = S[s + 3] * ee.w + kx.w * vl; a3 += qq.w * S[s + 3];
        }
        ag[base + (size_t)t * 1024 + lane] = __float2bfloat16(((a0 + a1) + (a2 + a3)) * gl);
    }
}

// ---------------- launch ----------------
extern "C" void kernel_launch(void* const* d_in, const int* in_sizes, int n_in,
                              void* d_out, int out_size, void* d_ws, size_t ws_size,
                              hipStream_t stream) {
    const float* x    = (const float*)d_in[0];
    const float* maax = (const float*)d_in[1];
    const float* maar = (const float*)d_in[2];
    const float* maak = (const float*)d_in[3];
    const float* maav = (const float*)d_in[4];
    const float* maaw = (const float*)d_in[5];
    const float* maag = (const float*)d_in[6];
    const float* w1   = (const float*)d_in[7];   // (1024,160)
    const float* w2   = (const float*)d_in[8];   // (5,32,1024)
    const float* td   = (const float*)d_in[9];   // (1024)
    const float* dw1  = (const float*)d_in[10];  // (1024,64)
    const float* dw2  = (const float*)d_in[11];  // (64,1024)
    const float* Wq   = (const float*)d_in[12];
    const float* Wk   = (const float*)d_in[13];
    const float* Wv   = (const float*)d_in[14];
    const float* Wo   = (const float*)d_in[15];
    const float* Wg   = (const float*)d_in[16];
    const float* bg   = (const float*)d_in[17];

    char* ws = (char*)d_ws;
    bf16*  xxx   = (bf16*) (ws + OFF_XXXQ);
    bf16*  qb    = (bf16*) (ws + OFF_XXXQ);   // reuse: xxx dead after mp gemm
    float* mp    = (float*)(ws + OFF_MP);
    bf16*  xs    = (bf16*) (ws + OFF_XSAG);   // per-stream buffer, reused 5x
    bf16*  ag    = (bf16*) (ws + OFF_XSAG);   // reuse: xs dead after gate gemm
    bf16*  dect  = (bf16*) (ws + OFF_DECT);
    bf16*  wb    = (bf16*) (ws + OFF_W);
    bf16*  kb    = (bf16*) (ws + OFF_K);
    bf16*  vb    = (bf16*) (ws + OFF_V);
    bf16*  gateb = (bf16*) (ws + OFF_GATE);
    bf16*  wqt   = (bf16*) (ws + OFF_WQT);
    bf16*  wkt   = (bf16*) (ws + OFF_WKT);
    bf16*  wvt   = (bf16*) (ws + OFF_WVT);
    bf16*  wgt   = (bf16*) (ws + OFF_WGT);
    bf16*  wot   = (bf16*) (ws + OFF_WOT);
    bf16*  w1t   = (bf16*) (ws + OFF_W1T);
    bf16*  wd1t  = (bf16*) (ws + OFF_WD1T);
    bf16*  wd2t  = (bf16*) (ws + OFF_WD2T);
    float* Sloc  = (float*)(ws + OFF_SLOC);   // reuse: wqt..wgt dead before scan
    float* Dbuf  = (float*)(ws + OFF_D);      // reuse: dect dead before scan

    dim3 tb(32, 8);
    transpose_pad<<<dim3(32, 32), tb, 0, stream>>>(Wq,  wqt, 1024, 1024, 1024);
    transpose_pad<<<dim3(32, 32), tb, 0, stream>>>(Wk,  wkt, 1024, 1024, 1024);
    transpose_pad<<<dim3(32, 32), tb, 0, stream>>>(Wv,  wvt, 1024, 1024, 1024);
    transpose_pad<<<dim3(32, 32), tb, 0, stream>>>(Wg,  wgt, 1024, 1024, 1024);
    transpose_pad<<<dim3(32, 32), tb, 0, stream>>>(Wo,  wot, 1024, 1024, 1024);
    transpose_pad<<<dim3(32,  8), tb, 0, stream>>>(w1,  w1t, 1024, 160,  256);
    transpose_pad<<<dim3(32,  4), tb, 0, stream>>>(dw1, wd1t, 1024, 64,  128);
    transpose_pad<<<dim3(2,  32), tb, 0, stream>>>(dw2, wd2t, 64,  1024, 1024);

    prep_xxx<<<16384, 256, 0, stream>>>(x, maax, xxx);

    // mp = tanh(xxx @ W1)   (4096,256 padded, f32)
    gemm_bt<1><<<dim3(32, 2), 256, 0, stream>>>(xxx, 1024, w1t, 1024, mp, 256, 1024, nullptr);

    // ---- stream w (f=3): decay chain -> wb = exp(decay) ----
    mix_stream<<<dim3(4, 1024), 256, 0, stream>>>(mp, w2, x, maaw, 3, xs);
    gemm_bt<2><<<dim3(32, 1), 256, 0, stream>>>(xs, 1024, wd1t, 1024, dect, 128, 1024, nullptr);
    gemm_bt<3><<<dim3(32, 8), 256, 0, stream>>>(dect, 128, wd2t, 64, wb, 1024, 64, td);

    // ---- stream r (f=0): q ----
    mix_stream<<<dim3(4, 1024), 256, 0, stream>>>(mp, w2, x, maar, 0, xs);
    gemm_bt<5><<<dim3(32, 8), 256, 0, stream>>>(xs, 1024, wqt, 1024, qb, 1024, 1024, nullptr);

    // ---- stream k (f=1) ----
    mix_stream<<<dim3(4, 1024), 256, 0, stream>>>(mp, w2, x, maak, 1, xs);
    gemm_bt<5><<<dim3(32, 8), 256, 0, stream>>>(xs, 1024, wkt, 1024, kb, 1024, 1024, nullptr);

    // ---- stream v (f=2) ----
    mix_stream<<<dim3(4, 1024), 256, 0, stream>>>(mp, w2, x, maav, 2, xs);
    gemm_bt<5><<<dim3(32, 8), 256, 0, stream>>>(xs, 1024, wvt, 1024, vb, 1024, 1024, nullptr);

    // ---- stream g (f=4): gate = silu(xg @ Wg + bg) ----
    mix_stream<<<dim3(4, 1024), 256, 0, stream>>>(mp, w2, x, maag, 4, xs);
    gemm_bt<4><<<dim3(32, 8), 256, 0, stream>>>(xs, 1024, wgt, 1024, gateb, 1024, 1024, bg);

    // ---- chunked scan (wqt..wgt + dect regions now dead -> Sloc/D) ----
    chunk_state  <<<dim3(16, 32),  64, 0, stream>>>(kb, vb, wb, Sloc, Dbuf);
    chunk_combine<<<32,           256, 0, stream>>>(Sloc, Dbuf);
    chunk_out    <<<dim3(16, 32),  64, 0, stream>>>(qb, kb, vb, wb, gateb, Sloc, ag);

    // out = (o*gate) @ Wo  -> f32 (reference output dtype)
    gemm_bt<6><<<dim3(32, 8), 256, 0, stream>>>(ag, 1024, wot, 1024, (float*)d_out, 1024, 1024, nullptr);

    (void)in_sizes; (void)n_in; (void)out_size; (void)ws_size;
}

// Round 7
// 567.233 us; speedup vs baseline: 3.8534x; 1.2024x over previous
//
#include <hip/hip_runtime.h>
#include <hip/hip_bf16.h>

typedef __hip_bfloat16 bf16;
typedef __bf16 bf16x8 __attribute__((ext_vector_type(8)));
typedef float f32x4 __attribute__((ext_vector_type(4)));

// ---------------- sizes ----------------
// B=2, T=2048, D=1024, H=16, HD=64; BT = 4096 rows. ALL inputs f32; output f32.
// Scan chunking: NC=32 chunks of L=64 per (b,h)  -> 1024 blocks, 4 waves/CU.
static constexpr size_t MB = 1ull << 20;

// ws layout (bytes), re-planned so scan-dead buffers are contiguous for Sloc(16 MiB):
static constexpr size_t OFF_XXXQ = 0;            // bf16 4096x1024: xxx, then q       [live in scan]
static constexpr size_t OFF_K    = 8  * MB;      // bf16 k                             [live]
static constexpr size_t OFF_V    = 16 * MB;      // bf16 v                             [live]
static constexpr size_t OFF_W    = 24 * MB;      // bf16 w=exp(decay)                  [live]
static constexpr size_t OFF_GATE = 32 * MB;      // bf16 gate -> ag IN-PLACE in chunk_out
static constexpr size_t OFF_WOT  = 40 * MB;      // bf16 1024x1024                     [live till final gemm]
static constexpr size_t OFF_W1T  = 42 * MB;                  // bf16 256x1024 (0.5 MiB)
static constexpr size_t OFF_WD1T = 42 * MB + 512 * 1024;     // bf16 128x1024 (0.25 MiB)
static constexpr size_t OFF_WD2T = 42 * MB + 768 * 1024;     // bf16 1024x64 (128 KiB)
static constexpr size_t OFF_MP   = 43 * MB;      // f32 4096x256 (4 MiB)   [dead at scan]
static constexpr size_t OFF_DECT = 47 * MB;      // bf16 4096x128 (1 MiB)  [dead at scan]
static constexpr size_t OFF_XS   = 48 * MB;      // bf16 4096x1024 (8 MiB) [dead at scan]
static constexpr size_t OFF_WQT  = 56 * MB;      // bf16 2 MiB             [dead at scan]
static constexpr size_t OFF_WKT  = 58 * MB;      // bf16 2 MiB             [dead at scan]
static constexpr size_t OFF_WVT  = 60 * MB;      // bf16 2 MiB
static constexpr size_t OFF_WGT  = 62 * MB;      // bf16 2 MiB
static constexpr size_t OFF_SLOC = 43 * MB;      // f32 [32bh][32c][64v][64k] = 16 MiB (43..59)
static constexpr size_t OFF_D    = 59 * MB;      // f32 [32bh][32c][64k] = 256 KiB (inside dead wkt)

// ---------------- helpers ----------------
__device__ __forceinline__ void async_ld16(const void* g, void* l) {
    __builtin_amdgcn_global_load_lds((const __attribute__((address_space(1))) void*)g,
                                     (__attribute__((address_space(3))) void*)l, 16, 0, 0);
}
__device__ __forceinline__ float bf2f(unsigned short u) {
    union { unsigned int i; float f; } x; x.i = ((unsigned int)u) << 16; return x.f;
}

// ---------------- fused transpose of all 8 weight mats (f32 -> bf16, col-pad) ----------------
__global__ void transpose_all(const float* __restrict__ Wq, const float* __restrict__ Wk,
                              const float* __restrict__ Wv, const float* __restrict__ Wg,
                              const float* __restrict__ Wo, const float* __restrict__ w1,
                              const float* __restrict__ dw1, const float* __restrict__ dw2,
                              bf16* __restrict__ wqt, bf16* __restrict__ wkt,
                              bf16* __restrict__ wvt, bf16* __restrict__ wgt,
                              bf16* __restrict__ wot, bf16* __restrict__ w1t,
                              bf16* __restrict__ wd1t, bf16* __restrict__ wd2t) {
    __shared__ bf16 tile[32][33];
    int id = blockIdx.x;
    const float* src; bf16* dst; int R, C, Cpad, local;
    if      (id < 1024) { src = Wq;  dst = wqt;  R = 1024; C = 1024; Cpad = 1024; local = id; }
    else if (id < 2048) { src = Wk;  dst = wkt;  R = 1024; C = 1024; Cpad = 1024; local = id - 1024; }
    else if (id < 3072) { src = Wv;  dst = wvt;  R = 1024; C = 1024; Cpad = 1024; local = id - 2048; }
    else if (id < 4096) { src = Wg;  dst = wgt;  R = 1024; C = 1024; Cpad = 1024; local = id - 3072; }
    else if (id < 5120) { src = Wo;  dst = wot;  R = 1024; C = 1024; Cpad = 1024; local = id - 4096; }
    else if (id < 5376) { src = w1;  dst = w1t;  R = 1024; C = 160;  Cpad = 256;  local = id - 5120; }
    else if (id < 5504) { src = dw1; dst = wd1t; R = 1024; C = 64;   Cpad = 128;  local = id - 5376; }
    else                { src = dw2; dst = wd2t; R = 64;   C = 1024; Cpad = 1024; local = id - 5504; }
    int Rb = R >> 5;
    int r0 = (local % Rb) * 32, c0 = (local / Rb) * 32;
    int tx = threadIdx.x, ty = threadIdx.y;  // block (32,8)
#pragma unroll
    for (int yy = 0; yy < 4; ++yy) {
        int r = r0 + ty + yy * 8, c = c0 + tx;
        float v = (r < R && c < C) ? src[(size_t)r * C + c] : 0.f;
        tile[ty + yy * 8][tx] = __float2bfloat16(v);
    }
    __syncthreads();
#pragma unroll
    for (int yy = 0; yy < 4; ++yy) {
        int c = c0 + ty + yy * 8, r = r0 + tx;
        if (c < Cpad && r < R) dst[(size_t)c * R + r] = tile[tx][ty + yy * 8];
    }
}

// ---------------- xxx = x + dxprev * maa_x ----------------
__global__ void prep_xxx(const float* __restrict__ x, const float* __restrict__ maa_x,
                         bf16* __restrict__ xxx) {
    int i = blockIdx.x * 256 + threadIdx.x;      // 0..4M-1
    int d = i & 1023;
    int t = (i >> 10) & 2047;
    float xv = x[i];
    float xp = (t > 0) ? x[i - 1024] : 0.f;
    xxx[i] = __float2bfloat16(xv + (xp - xv) * maa_x[d]);
}

// ---------------- m97-style bf16 MFMA GEMM: C(M,N) = A(M,K) @ Bt(N,K)^T ----------------
// EPI: 1 = f32 tanh; 2 = bf16 tanh; 3 = bf16 w=exp(aux+v); 4 = bf16 silu(v+aux);
//      5 = bf16 plain; 6 = f32 plain
template<int EPI>
__global__ __launch_bounds__(256)
void gemm_bt(const bf16* __restrict__ A, int lda,
             const bf16* __restrict__ Bt, int ldb,
             void* __restrict__ Cout, int ldc,
             int K, const float* __restrict__ aux)
{
    __shared__ __align__(16) bf16 As[128 * 32];
    __shared__ __align__(16) bf16 Bs[128 * 32];
    const int m0 = blockIdx.x * 128;
    const int n0 = blockIdx.y * 128;
    const int tid = threadIdx.x;
    const int lane = tid & 63;
    const int w = tid >> 6;
    const int wm = w >> 1, wn = w & 1;
    const int row16 = lane & 15;
    const int quad = lane >> 4;

    f32x4 acc[4][4];
#pragma unroll
    for (int mi = 0; mi < 4; ++mi)
#pragma unroll
        for (int ni = 0; ni < 4; ++ni)
            acc[mi][ni] = (f32x4){0.f, 0.f, 0.f, 0.f};

    for (int k0 = 0; k0 < K; k0 += 32) {
        __syncthreads();
#pragma unroll
        for (int j = 0; j < 2; ++j) {
            int i = j * 256 + w * 64 + lane;
            int ri = i >> 2;
            int ci = (i & 3) * 8;
            const bf16* ga = A  + (size_t)(m0 + ri) * lda + (k0 + ci);
            const bf16* gb = Bt + (size_t)(n0 + ri) * ldb + (k0 + ci);
            bf16* la = As + (size_t)(j * 256 + w * 64) * 8;
            bf16* lb = Bs + (size_t)(j * 256 + w * 64) * 8;
            async_ld16(ga, la);
            async_ld16(gb, lb);
        }
        __syncthreads();
        bf16x8 af[4], bfr[4];
#pragma unroll
        for (int mi = 0; mi < 4; ++mi)
            af[mi] = *(const bf16x8*)(As + ((wm * 64 + mi * 16 + row16) * 32 + quad * 8));
#pragma unroll
        for (int ni = 0; ni < 4; ++ni)
            bfr[ni] = *(const bf16x8*)(Bs + ((wn * 64 + ni * 16 + row16) * 32 + quad * 8));
#pragma unroll
        for (int mi = 0; mi < 4; ++mi)
#pragma unroll
            for (int ni = 0; ni < 4; ++ni)
                acc[mi][ni] = __builtin_amdgcn_mfma_f32_16x16x32_bf16(af[mi], bfr[ni], acc[mi][ni], 0, 0, 0);
    }
#pragma unroll
    for (int mi = 0; mi < 4; ++mi)
#pragma unroll
        for (int ni = 0; ni < 4; ++ni)
#pragma unroll
            for (int r = 0; r < 4; ++r) {
                int gr = m0 + wm * 64 + mi * 16 + quad * 4 + r;
                int gc = n0 + wn * 64 + ni * 16 + row16;
                size_t ci = (size_t)gr * ldc + gc;
                float v = acc[mi][ni][r];
                if (EPI == 1) ((float*)Cout)[ci] = tanhf(v);
                else if (EPI == 2) ((bf16*)Cout)[ci] = __float2bfloat16(tanhf(v));
                else if (EPI == 3) {
                    float t = aux[gc] + v;
                    ((bf16*)Cout)[ci] = __float2bfloat16(expf(t));   // w = exp(decay)
                } else if (EPI == 4) {
                    float z = v + aux[gc];
                    ((bf16*)Cout)[ci] = __float2bfloat16(z / (1.f + expf(-z)));  // silu
                } else if (EPI == 5) {
                    ((bf16*)Cout)[ci] = __float2bfloat16(v);
                } else {
                    ((float*)Cout)[ci] = v;   // EPI 6: f32 plain (final output)
                }
            }
}

// ---------------- one stream: xs = x + dxprev * (maa_f + mp_f @ w2_f) ----------------
__global__ __launch_bounds__(256)
void mix_stream(const float* __restrict__ mp,    // (4096,256) f32, cols [f*32,f*32+32)
                const float* __restrict__ w2,    // (5,32,1024)
                const float* __restrict__ x,
                const float* __restrict__ maa_f,
                int f,
                bf16* __restrict__ xs)
{
    __shared__ float mps[4][32];
    int dg = blockIdx.x;          // 0..3
    int r0 = blockIdx.y * 4;      // 4 rows per block
    int tid = threadIdx.x;
    int d = dg * 256 + tid;
    if (tid < 128) {
        int rr = tid >> 5, l = tid & 31;
        mps[rr][l] = mp[(size_t)(r0 + rr) * 256 + f * 32 + l];
    }
    __syncthreads();
    float acc[4] = {0.f, 0.f, 0.f, 0.f};
#pragma unroll
    for (int l = 0; l < 32; ++l) {
        float wv = w2[(size_t)(f * 32 + l) * 1024 + d];
#pragma unroll
        for (int rr = 0; rr < 4; ++rr)
            acc[rr] = fmaf(mps[rr][l], wv, acc[rr]);
    }
    float mf = maa_f[d];
#pragma unroll
    for (int rr = 0; rr < 4; ++rr) {
        int r = r0 + rr;
        int t = r & 2047;
        size_t i = (size_t)r * 1024 + d;
        float xv = x[i];
        float xp = (t > 0) ? x[i - 1024] : 0.f;
        xs[i] = __float2bfloat16(xv + (xp - xv) * (mf + acc[rr]));
    }
}

// ================= chunked gated-linear-attention scan (NC=32, L=64) =================
// Phase A: per (bh, c): local end-state Sloc[v][k] from zero init, and per-k decay
// product D[k]. lane = k; v broadcast via LDS.
__global__ __launch_bounds__(64)
void chunk_state(const bf16* __restrict__ k, const bf16* __restrict__ v,
                 const bf16* __restrict__ w,
                 float* __restrict__ Sloc, float* __restrict__ D)
{
    int c = blockIdx.x, bh = blockIdx.y;
    int b = bh >> 4, h = bh & 15;
    int lane = threadIdx.x;            // k index
    __shared__ __align__(16) float sh[2][64];   // v broadcast
    size_t base = (size_t)b * 2048 * 1024 + (size_t)h * 64 + (size_t)c * 64 * 1024;

    float S[64];                       // S[v] for k = lane
#pragma unroll
    for (int i = 0; i < 64; ++i) S[i] = 0.f;
    float Dl = 1.f;

    const unsigned short* kp = (const unsigned short*)k;
    const unsigned short* vp = (const unsigned short*)v;
    const unsigned short* wp = (const unsigned short*)w;
    unsigned short kr[4], vr[4], wr[4];
#pragma unroll
    for (int j = 0; j < 4; ++j) {
        size_t a = base + (size_t)j * 1024 + lane;
        kr[j] = kp[a]; vr[j] = vp[a]; wr[j] = wp[a];
    }
    for (int t = 0; t < 64; ++t) {
        int slot = t & 3, p = t & 1;
        float kl = bf2f(kr[slot]);
        float vl = bf2f(vr[slot]);
        float wl = bf2f(wr[slot]);
        if (t + 4 < 64) {
            size_t a = base + (size_t)(t + 4) * 1024 + lane;
            kr[slot] = kp[a]; vr[slot] = vp[a]; wr[slot] = wp[a];
        }
        float el = __expf(-wl);        // decay for k=lane
        float kb = kl * (1.f - el);    // k bonus
        Dl *= el;
        sh[p][lane] = vl;
        __syncthreads();
        const float4* v4 = (const float4*)sh[p];
#pragma unroll
        for (int vv = 0; vv < 16; ++vv) {
            float4 vx = v4[vv];
            int s = vv * 4;
            S[s + 0] = S[s + 0] * el + kb * vx.x;
            S[s + 1] = S[s + 1] * el + kb * vx.y;
            S[s + 2] = S[s + 2] * el + kb * vx.z;
            S[s + 3] = S[s + 3] * el + kb * vx.w;
        }
    }
    float* So = Sloc + ((size_t)bh * 32 + c) * 4096;
#pragma unroll
    for (int i = 0; i < 64; ++i) So[(size_t)i * 64 + lane] = S[i];
    D[((size_t)bh * 32 + c) * 64 + lane] = Dl;
}

// Phase B: sequential combine over chunks (exact): S0_{c+1} = S0_c*D_c + Sloc_c.
// Overwrites Sloc_c with S0_c (state at chunk start). Parallel over (v,k).
__global__ __launch_bounds__(256)
void chunk_combine(float* __restrict__ Sloc, const float* __restrict__ D)
{
    int bh = blockIdx.x;
    int tid = threadIdx.x;
    int k = tid & 63, v0 = tid >> 6;
#pragma unroll
    for (int j = 0; j < 16; ++j) {
        int v = v0 + j * 4;
        float s = 0.f;
        for (int c = 0; c < 32; ++c) {
            size_t idx = ((size_t)bh * 32 + c) * 4096 + (size_t)v * 64 + k;
            float tmp = Sloc[idx];
            Sloc[idx] = s;
            s = s * D[((size_t)bh * 32 + c) * 64 + k] + tmp;
        }
    }
}

// Phase C: per (bh, c): recurrence from S0_c producing outputs, gate fused.
// lane = v; S[k] in regs; gate buffer consumed IN-PLACE (ag == gate is safe:
// each element is read, then overwritten by the same thread in the same step;
// prefetch only reads t+4 > t).
__global__ __launch_bounds__(64)
void chunk_out(const bf16* __restrict__ q, const bf16* __restrict__ k,
               const bf16* __restrict__ v, const bf16* __restrict__ w,
               const bf16* gate, const float* __restrict__ S0buf,
               bf16* ag)
{
    int c = blockIdx.x, bh = blockIdx.y;
    int b = bh >> 4, h = bh & 15;
    int lane = threadIdx.x;            // v index
    __shared__ __align__(16) float sh[2][3][64];
    size_t base = (size_t)b * 2048 * 1024 + (size_t)h * 64 + (size_t)c * 64 * 1024;

    float S[64];
    const float4* S0 = (const float4*)(S0buf + ((size_t)bh * 32 + c) * 4096 + (size_t)lane * 64);
#pragma unroll
    for (int i = 0; i < 16; ++i) {
        float4 x4 = S0[i];
        S[i * 4 + 0] = x4.x; S[i * 4 + 1] = x4.y; S[i * 4 + 2] = x4.z; S[i * 4 + 3] = x4.w;
    }

    const unsigned short* qp = (const unsigned short*)q;
    const unsigned short* kp = (const unsigned short*)k;
    const unsigned short* vp = (const unsigned short*)v;
    const unsigned short* wp = (const unsigned short*)w;
    const unsigned short* gp = (const unsigned short*)gate;
    unsigned short qr[4], kr[4], vr[4], wr[4], gr[4];
#pragma unroll
    for (int j = 0; j < 4; ++j) {
        size_t a = base + (size_t)j * 1024 + lane;
        qr[j] = qp[a]; kr[j] = kp[a]; vr[j] = vp[a]; wr[j] = wp[a]; gr[j] = gp[a];
    }
    for (int t = 0; t < 64; ++t) {
        int slot = t & 3, p = t & 1;
        float ql = bf2f(qr[slot]) * 0.125f;   // HD^-0.5
        float kl = bf2f(kr[slot]);
        float vl = bf2f(vr[slot]);
        float wl = bf2f(wr[slot]);
        float gl = bf2f(gr[slot]);
        if (t + 4 < 64) {
            size_t a = base + (size_t)(t + 4) * 1024 + lane;
            qr[slot] = qp[a]; kr[slot] = kp[a]; vr[slot] = vp[a];
            wr[slot] = wp[a]; gr[slot] = gp[a];
        }
        float el = __expf(-wl);
        sh[p][0][lane] = ql;
        sh[p][1][lane] = kl * (1.f - el);
        sh[p][2][lane] = el;
        __syncthreads();
        const float4* q4 = (const float4*)sh[p][0];
        const float4* k4 = (const float4*)sh[p][1];
        const float4* e4 = (const float4*)sh[p][2];
        float a0 = 0.f, a1 = 0.f, a2 = 0.f, a3 = 0.f;
#pragma unroll
        for (int kk = 0; kk < 16; ++kk) {
            float4 qq = q4[kk], kx = k4[kk], ee = e4[kk];
            int s = kk * 4;
            S[s + 0] = S[s + 0] * ee.x + kx.x * vl; a0 += qq.x * S[s + 0];
            S[s + 1] = S[s + 1] * ee.y + kx.y * vl; a1 += qq.y * S[s + 1];
            S[s + 2] = S[s + 2] * ee.z + kx.z * vl; a2 += qq.z * S[s + 2];
            S[s + 3] = S[s + 3] * ee.w + kx.w * vl; a3 += qq.w * S[s + 3];
        }
        ag[base + (size_t)t * 1024 + lane] = __float2bfloat16(((a0 + a1) + (a2 + a3)) * gl);
    }
}

// ---------------- launch ----------------
extern "C" void kernel_launch(void* const* d_in, const int* in_sizes, int n_in,
                              void* d_out, int out_size, void* d_ws, size_t ws_size,
                              hipStream_t stream) {
    const float* x    = (const float*)d_in[0];
    const float* maax = (const float*)d_in[1];
    const float* maar = (const float*)d_in[2];
    const float* maak = (const float*)d_in[3];
    const float* maav = (const float*)d_in[4];
    const float* maaw = (const float*)d_in[5];
    const float* maag = (const float*)d_in[6];
    const float* w1   = (const float*)d_in[7];   // (1024,160)
    const float* w2   = (const float*)d_in[8];   // (5,32,1024)
    const float* td   = (const float*)d_in[9];   // (1024)
    const float* dw1  = (const float*)d_in[10];  // (1024,64)
    const float* dw2  = (const float*)d_in[11];  // (64,1024)
    const float* Wq   = (const float*)d_in[12];
    const float* Wk   = (const float*)d_in[13];
    const float* Wv   = (const float*)d_in[14];
    const float* Wo   = (const float*)d_in[15];
    const float* Wg   = (const float*)d_in[16];
    const float* bg   = (const float*)d_in[17];

    char* ws = (char*)d_ws;
    bf16*  xxx   = (bf16*) (ws + OFF_XXXQ);
    bf16*  qb    = (bf16*) (ws + OFF_XXXQ);   // reuse: xxx dead after mp gemm
    bf16*  kb    = (bf16*) (ws + OFF_K);
    bf16*  vb    = (bf16*) (ws + OFF_V);
    bf16*  wb    = (bf16*) (ws + OFF_W);
    bf16*  gateb = (bf16*) (ws + OFF_GATE);   // gate, consumed in-place -> ag
    bf16*  wot   = (bf16*) (ws + OFF_WOT);
    bf16*  w1t   = (bf16*) (ws + OFF_W1T);
    bf16*  wd1t  = (bf16*) (ws + OFF_WD1T);
    bf16*  wd2t  = (bf16*) (ws + OFF_WD2T);
    float* mp    = (float*)(ws + OFF_MP);
    bf16*  dect  = (bf16*) (ws + OFF_DECT);
    bf16*  xs    = (bf16*) (ws + OFF_XS);
    bf16*  wqt   = (bf16*) (ws + OFF_WQT);
    bf16*  wkt   = (bf16*) (ws + OFF_WKT);
    bf16*  wvt   = (bf16*) (ws + OFF_WVT);
    bf16*  wgt   = (bf16*) (ws + OFF_WGT);
    float* Sloc  = (float*)(ws + OFF_SLOC);   // overlays mp/dect/xs/wqt/wkt (dead at scan)
    float* Dbuf  = (float*)(ws + OFF_D);      // overlays dead wkt tail

    transpose_all<<<5568, dim3(32, 8), 0, stream>>>(Wq, Wk, Wv, Wg, Wo, w1, dw1, dw2,
                                                    wqt, wkt, wvt, wgt, wot, w1t, wd1t, wd2t);

    prep_xxx<<<16384, 256, 0, stream>>>(x, maax, xxx);

    // mp = tanh(xxx @ W1)   (4096,256 padded, f32)
    gemm_bt<1><<<dim3(32, 2), 256, 0, stream>>>(xxx, 1024, w1t, 1024, mp, 256, 1024, nullptr);

    // ---- stream w (f=3): decay chain -> wb = exp(decay) ----
    mix_stream<<<dim3(4, 1024), 256, 0, stream>>>(mp, w2, x, maaw, 3, xs);
    gemm_bt<2><<<dim3(32, 1), 256, 0, stream>>>(xs, 1024, wd1t, 1024, dect, 128, 1024, nullptr);
    gemm_bt<3><<<dim3(32, 8), 256, 0, stream>>>(dect, 128, wd2t, 64, wb, 1024, 64, td);

    // ---- stream r (f=0): q ----
    mix_stream<<<dim3(4, 1024), 256, 0, stream>>>(mp, w2, x, maar, 0, xs);
    gemm_bt<5><<<dim3(32, 8), 256, 0, stream>>>(xs, 1024, wqt, 1024, qb, 1024, 1024, nullptr);

    // ---- stream k (f=1) ----
    mix_stream<<<dim3(4, 1024), 256, 0, stream>>>(mp, w2, x, maak, 1, xs);
    gemm_bt<5><<<dim3(32, 8), 256, 0, stream>>>(xs, 1024, wkt, 1024, kb, 1024, 1024, nullptr);

    // ---- stream v (f=2) ----
    mix_stream<<<dim3(4, 1024), 256, 0, stream>>>(mp, w2, x, maav, 2, xs);
    gemm_bt<5><<<dim3(32, 8), 256, 0, stream>>>(xs, 1024, wvt, 1024, vb, 1024, 1024, nullptr);

    // ---- stream g (f=4): gate = silu(xg @ Wg + bg) ----
    mix_stream<<<dim3(4, 1024), 256, 0, stream>>>(mp, w2, x, maag, 4, xs);
    gemm_bt<4><<<dim3(32, 8), 256, 0, stream>>>(xs, 1024, wgt, 1024, gateb, 1024, 1024, bg);

    // ---- chunked scan: NC=32, L=64; Sloc overlays dead mp/dect/xs/wqt/wkt ----
    chunk_state  <<<dim3(32, 32),  64, 0, stream>>>(kb, vb, wb, Sloc, Dbuf);
    chunk_combine<<<32,           256, 0, stream>>>(Sloc, Dbuf);
    chunk_out    <<<dim3(32, 32),  64, 0, stream>>>(qb, kb, vb, wb, gateb, Sloc, gateb);

    // out = (o*gate) @ Wo  -> f32 (reference output dtype)
    gemm_bt<6><<<dim3(32, 8), 256, 0, stream>>>(gateb, 1024, wot, 1024, (float*)d_out, 1024, 1024, nullptr);

    (void)in_sizes; (void)n_in; (void)out_size; (void)ws_size;
}

// Round 8
// 502.172 us; speedup vs baseline: 4.3527x; 1.1296x over previous
//
#include <hip/hip_runtime.h>
#include <hip/hip_bf16.h>

typedef __hip_bfloat16 bf16;
typedef __bf16 bf16x8 __attribute__((ext_vector_type(8)));
typedef float f32x4 __attribute__((ext_vector_type(4)));
typedef _Float16 h8 __attribute__((ext_vector_type(8)));

// ---------------- sizes ----------------
// B=2, T=2048, D=1024, H=16, HD=64; BT=4096 rows. Inputs f32; output f32.
// Scan: NC=64 chunks of L=32 -> 2048 blocks (8 blocks/CU). Sloc f16.
static constexpr size_t MB = 1ull << 20;
static constexpr size_t KB = 1024;

// ws layout (<= 64 MiB), lifetime-packed:
static constexpr size_t OFF_XXXQ = 0;              // bf16 8MB: xxx, then q
static constexpr size_t OFF_K    = 8 * MB;         // bf16 8MB
static constexpr size_t OFF_V    = 16 * MB;        // bf16 8MB
static constexpr size_t OFF_W    = 24 * MB;        // bf16 8MB  wb = exp(decay)
static constexpr size_t OFF_WQT  = 32 * MB;        // bf16 2MB  [dead after qk gemm]
static constexpr size_t OFF_WKT  = 34 * MB;        // bf16 2MB  [dead after qk gemm]
static constexpr size_t OFF_MP   = 36 * MB;        // f32  4MB  [dead after vg mix]
static constexpr size_t OFF_GATE = 32 * MB;        // bf16 8MB: overwrites wqt/wkt/mp; -> ag in-place
static constexpr size_t OFF_XS0  = 40 * MB;        // bf16 8MB  [dead at scan]
static constexpr size_t OFF_XS1  = 48 * MB;        // bf16 8MB  [dead at scan]
static constexpr size_t OFF_SLOC = 40 * MB;        // f16 [32bh][64c][64v][64k] = 16MB (overlays xs0/xs1)
static constexpr size_t OFF_WVT  = 56 * MB;        // bf16 2MB
static constexpr size_t OFF_WGT  = 58 * MB;        // bf16 2MB
static constexpr size_t OFF_WOT  = 60 * MB;        // bf16 2MB (live till final gemm)
static constexpr size_t OFF_W1T  = 62 * MB;        // bf16 0.5MB [dead after mp gemm]
static constexpr size_t OFF_D    = 62 * MB;        // f32 [32][64][64] = 0.5MB (overlays dead w1t)
static constexpr size_t OFF_WD1T = 62 * MB + 512 * KB;   // bf16 0.25MB
static constexpr size_t OFF_WD2T = 62 * MB + 768 * KB;   // bf16 0.125MB
static constexpr size_t OFF_DECT = 63 * MB;        // bf16 1MB

// ---------------- helpers ----------------
__device__ __forceinline__ void async_ld16(const void* g, void* l) {
    __builtin_amdgcn_global_load_lds((const __attribute__((address_space(1))) void*)g,
                                     (__attribute__((address_space(3))) void*)l, 16, 0, 0);
}
__device__ __forceinline__ float bf2f(unsigned short u) {
    union { unsigned int i; float f; } x; x.i = ((unsigned int)u) << 16; return x.f;
}

// ---------------- fused transpose of all 8 weight mats (f32 -> bf16, col-pad) ----------------
__global__ void transpose_all(const float* __restrict__ Wq, const float* __restrict__ Wk,
                              const float* __restrict__ Wv, const float* __restrict__ Wg,
                              const float* __restrict__ Wo, const float* __restrict__ w1,
                              const float* __restrict__ dw1, const float* __restrict__ dw2,
                              bf16* __restrict__ wqt, bf16* __restrict__ wkt,
                              bf16* __restrict__ wvt, bf16* __restrict__ wgt,
                              bf16* __restrict__ wot, bf16* __restrict__ w1t,
                              bf16* __restrict__ wd1t, bf16* __restrict__ wd2t) {
    __shared__ bf16 tile[32][33];
    int id = blockIdx.x;
    const float* src; bf16* dst; int R, C, Cpad, local;
    if      (id < 1024) { src = Wq;  dst = wqt;  R = 1024; C = 1024; Cpad = 1024; local = id; }
    else if (id < 2048) { src = Wk;  dst = wkt;  R = 1024; C = 1024; Cpad = 1024; local = id - 1024; }
    else if (id < 3072) { src = Wv;  dst = wvt;  R = 1024; C = 1024; Cpad = 1024; local = id - 2048; }
    else if (id < 4096) { src = Wg;  dst = wgt;  R = 1024; C = 1024; Cpad = 1024; local = id - 3072; }
    else if (id < 5120) { src = Wo;  dst = wot;  R = 1024; C = 1024; Cpad = 1024; local = id - 4096; }
    else if (id < 5376) { src = w1;  dst = w1t;  R = 1024; C = 160;  Cpad = 256;  local = id - 5120; }
    else if (id < 5504) { src = dw1; dst = wd1t; R = 1024; C = 64;   Cpad = 128;  local = id - 5376; }
    else                { src = dw2; dst = wd2t; R = 64;   C = 1024; Cpad = 1024; local = id - 5504; }
    int Rb = R >> 5;
    int r0 = (local % Rb) * 32, c0 = (local / Rb) * 32;
    int tx = threadIdx.x, ty = threadIdx.y;  // block (32,8)
#pragma unroll
    for (int yy = 0; yy < 4; ++yy) {
        int r = r0 + ty + yy * 8, c = c0 + tx;
        float v = (r < R && c < C) ? src[(size_t)r * C + c] : 0.f;
        tile[ty + yy * 8][tx] = __float2bfloat16(v);
    }
    __syncthreads();
#pragma unroll
    for (int yy = 0; yy < 4; ++yy) {
        int c = c0 + ty + yy * 8, r = r0 + tx;
        if (c < Cpad && r < R) dst[(size_t)c * R + r] = tile[tx][ty + yy * 8];
    }
}

// ---------------- xxx = x + dxprev * maa_x ----------------
__global__ void prep_xxx(const float* __restrict__ x, const float* __restrict__ maa_x,
                         bf16* __restrict__ xxx) {
    int i = blockIdx.x * 256 + threadIdx.x;      // 0..4M-1
    int d = i & 1023;
    int t = (i >> 10) & 2047;
    float xv = x[i];
    float xp = (t > 0) ? x[i - 1024] : 0.f;
    xxx[i] = __float2bfloat16(xv + (xp - xv) * maa_x[d]);
}

// ---------------- m97-style bf16 MFMA GEMM: C(M,N) = A(M,K) @ Bt(N,K)^T ----------------
// EPI: 1 = f32 tanh; 2 = bf16 tanh; 3 = bf16 w=exp(aux+v); 6 = f32 plain
template<int EPI>
__global__ __launch_bounds__(256)
void gemm_bt(const bf16* __restrict__ A, int lda,
             const bf16* __restrict__ Bt, int ldb,
             void* __restrict__ Cout, int ldc,
             int K, const float* __restrict__ aux)
{
    __shared__ __align__(16) bf16 As[128 * 32];
    __shared__ __align__(16) bf16 Bs[128 * 32];
    const int m0 = blockIdx.x * 128;
    const int n0 = blockIdx.y * 128;
    const int tid = threadIdx.x;
    const int lane = tid & 63;
    const int w = tid >> 6;
    const int wm = w >> 1, wn = w & 1;
    const int row16 = lane & 15;
    const int quad = lane >> 4;

    f32x4 acc[4][4];
#pragma unroll
    for (int mi = 0; mi < 4; ++mi)
#pragma unroll
        for (int ni = 0; ni < 4; ++ni)
            acc[mi][ni] = (f32x4){0.f, 0.f, 0.f, 0.f};

    for (int k0 = 0; k0 < K; k0 += 32) {
        __syncthreads();
#pragma unroll
        for (int j = 0; j < 2; ++j) {
            int i = j * 256 + w * 64 + lane;
            int ri = i >> 2;
            int ci = (i & 3) * 8;
            async_ld16(A  + (size_t)(m0 + ri) * lda + (k0 + ci), As + (size_t)(j * 256 + w * 64) * 8);
            async_ld16(Bt + (size_t)(n0 + ri) * ldb + (k0 + ci), Bs + (size_t)(j * 256 + w * 64) * 8);
        }
        __syncthreads();
        bf16x8 af[4], bfr[4];
#pragma unroll
        for (int mi = 0; mi < 4; ++mi)
            af[mi] = *(const bf16x8*)(As + ((wm * 64 + mi * 16 + row16) * 32 + quad * 8));
#pragma unroll
        for (int ni = 0; ni < 4; ++ni)
            bfr[ni] = *(const bf16x8*)(Bs + ((wn * 64 + ni * 16 + row16) * 32 + quad * 8));
#pragma unroll
        for (int mi = 0; mi < 4; ++mi)
#pragma unroll
            for (int ni = 0; ni < 4; ++ni)
                acc[mi][ni] = __builtin_amdgcn_mfma_f32_16x16x32_bf16(af[mi], bfr[ni], acc[mi][ni], 0, 0, 0);
    }
#pragma unroll
    for (int mi = 0; mi < 4; ++mi)
#pragma unroll
        for (int ni = 0; ni < 4; ++ni)
#pragma unroll
            for (int r = 0; r < 4; ++r) {
                int gr = m0 + wm * 64 + mi * 16 + quad * 4 + r;
                int gc = n0 + wn * 64 + ni * 16 + row16;
                size_t ci = (size_t)gr * ldc + gc;
                float v = acc[mi][ni][r];
                if (EPI == 1) ((float*)Cout)[ci] = tanhf(v);
                else if (EPI == 2) ((bf16*)Cout)[ci] = __float2bfloat16(tanhf(v));
                else if (EPI == 3) {
                    float t = aux[gc] + v;
                    ((bf16*)Cout)[ci] = __float2bfloat16(expf(t));   // w = exp(decay)
                } else {
                    ((float*)Cout)[ci] = v;   // EPI 6
                }
            }
}

// ---------------- batched z=2 GEMM: z selects (A,B,C); z=0 bf16 plain, z=1 EPI1 ----------------
// EPI1: 4 = bf16 silu(v+aux); 5 = bf16 plain
template<int EPI1>
__global__ __launch_bounds__(256)
void gemm_bt2(const bf16* __restrict__ A0, const bf16* __restrict__ A1, int lda,
              const bf16* __restrict__ B0, const bf16* __restrict__ B1, int ldb,
              bf16* __restrict__ C0, bf16* __restrict__ C1, int ldc,
              int K, const float* __restrict__ aux)
{
    __shared__ __align__(16) bf16 As[128 * 32];
    __shared__ __align__(16) bf16 Bs[128 * 32];
    const int z = blockIdx.z;
    const bf16* A  = z ? A1 : A0;
    const bf16* Bt = z ? B1 : B0;
    bf16* Cout     = z ? C1 : C0;
    const int m0 = blockIdx.x * 128;
    const int n0 = blockIdx.y * 128;
    const int tid = threadIdx.x;
    const int lane = tid & 63;
    const int w = tid >> 6;
    const int wm = w >> 1, wn = w & 1;
    const int row16 = lane & 15;
    const int quad = lane >> 4;

    f32x4 acc[4][4];
#pragma unroll
    for (int mi = 0; mi < 4; ++mi)
#pragma unroll
        for (int ni = 0; ni < 4; ++ni)
            acc[mi][ni] = (f32x4){0.f, 0.f, 0.f, 0.f};

    for (int k0 = 0; k0 < K; k0 += 32) {
        __syncthreads();
#pragma unroll
        for (int j = 0; j < 2; ++j) {
            int i = j * 256 + w * 64 + lane;
            int ri = i >> 2;
            int ci = (i & 3) * 8;
            async_ld16(A  + (size_t)(m0 + ri) * lda + (k0 + ci), As + (size_t)(j * 256 + w * 64) * 8);
            async_ld16(Bt + (size_t)(n0 + ri) * ldb + (k0 + ci), Bs + (size_t)(j * 256 + w * 64) * 8);
        }
        __syncthreads();
        bf16x8 af[4], bfr[4];
#pragma unroll
        for (int mi = 0; mi < 4; ++mi)
            af[mi] = *(const bf16x8*)(As + ((wm * 64 + mi * 16 + row16) * 32 + quad * 8));
#pragma unroll
        for (int ni = 0; ni < 4; ++ni)
            bfr[ni] = *(const bf16x8*)(Bs + ((wn * 64 + ni * 16 + row16) * 32 + quad * 8));
#pragma unroll
        for (int mi = 0; mi < 4; ++mi)
#pragma unroll
            for (int ni = 0; ni < 4; ++ni)
                acc[mi][ni] = __builtin_amdgcn_mfma_f32_16x16x32_bf16(af[mi], bfr[ni], acc[mi][ni], 0, 0, 0);
    }
#pragma unroll
    for (int mi = 0; mi < 4; ++mi)
#pragma unroll
        for (int ni = 0; ni < 4; ++ni)
#pragma unroll
            for (int r = 0; r < 4; ++r) {
                int gr = m0 + wm * 64 + mi * 16 + quad * 4 + r;
                int gc = n0 + wn * 64 + ni * 16 + row16;
                size_t ci = (size_t)gr * ldc + gc;
                float v = acc[mi][ni][r];
                if (z == 0 || EPI1 == 5) Cout[ci] = __float2bfloat16(v);
                else {
                    float zz = v + aux[gc];
                    Cout[ci] = __float2bfloat16(zz / (1.f + expf(-zz)));  // silu
                }
            }
}

// ---------------- single stream: xs = x + dxprev * (maa_f + mp_f @ w2_f) ----------------
__global__ __launch_bounds__(256)
void mix_stream(const float* __restrict__ mp, const float* __restrict__ w2,
                const float* __restrict__ x, const float* __restrict__ maa_f,
                int f, bf16* __restrict__ xs)
{
    __shared__ float mps[4][32];
    int dg = blockIdx.x, r0 = blockIdx.y * 4, tid = threadIdx.x;
    int d = dg * 256 + tid;
    if (tid < 128) {
        int rr = tid >> 5, l = tid & 31;
        mps[rr][l] = mp[(size_t)(r0 + rr) * 256 + f * 32 + l];
    }
    __syncthreads();
    float acc[4] = {0.f, 0.f, 0.f, 0.f};
#pragma unroll
    for (int l = 0; l < 32; ++l) {
        float wv = w2[(size_t)(f * 32 + l) * 1024 + d];
#pragma unroll
        for (int rr = 0; rr < 4; ++rr) acc[rr] = fmaf(mps[rr][l], wv, acc[rr]);
    }
    float mf = maa_f[d];
#pragma unroll
    for (int rr = 0; rr < 4; ++rr) {
        int r = r0 + rr, t = r & 2047;
        size_t i = (size_t)r * 1024 + d;
        float xv = x[i];
        float xp = (t > 0) ? x[i - 1024] : 0.f;
        xs[i] = __float2bfloat16(xv + (xp - xv) * (mf + acc[rr]));
    }
}

// ---------------- fused pair of streams sharing x/mp loads ----------------
__global__ __launch_bounds__(256)
void mix_stream2(const float* __restrict__ mp, const float* __restrict__ w2,
                 const float* __restrict__ x,
                 const float* __restrict__ maa_a, const float* __restrict__ maa_b,
                 int fa, int fb, bf16* __restrict__ xsa, bf16* __restrict__ xsb)
{
    __shared__ float mpsa[4][32], mpsb[4][32];
    int dg = blockIdx.x, r0 = blockIdx.y * 4, tid = threadIdx.x;
    int d = dg * 256 + tid;
    if (tid < 128) {
        int rr = tid >> 5, l = tid & 31;
        mpsa[rr][l] = mp[(size_t)(r0 + rr) * 256 + fa * 32 + l];
        mpsb[rr][l] = mp[(size_t)(r0 + rr) * 256 + fb * 32 + l];
    }
    __syncthreads();
    float acca[4] = {0.f, 0.f, 0.f, 0.f}, accb[4] = {0.f, 0.f, 0.f, 0.f};
#pragma unroll
    for (int l = 0; l < 32; ++l) {
        float wa = w2[(size_t)(fa * 32 + l) * 1024 + d];
        float wbv = w2[(size_t)(fb * 32 + l) * 1024 + d];
#pragma unroll
        for (int rr = 0; rr < 4; ++rr) {
            acca[rr] = fmaf(mpsa[rr][l], wa, acca[rr]);
            accb[rr] = fmaf(mpsb[rr][l], wbv, accb[rr]);
        }
    }
    float ma = maa_a[d], mb = maa_b[d];
#pragma unroll
    for (int rr = 0; rr < 4; ++rr) {
        int r = r0 + rr, t = r & 2047;
        size_t i = (size_t)r * 1024 + d;
        float xv = x[i];
        float xp = (t > 0) ? x[i - 1024] : 0.f;
        float dx = xp - xv;
        xsa[i] = __float2bfloat16(xv + dx * (ma + acca[rr]));
        xsb[i] = __float2bfloat16(xv + dx * (mb + accb[rr]));
    }
}

// ================= chunked scan: NC=64, L=32, f16 inter-chunk state =================
// Phase A: local end-state Sloc[v][k] (f16) + per-k decay product D[k]. lane = k.
__global__ __launch_bounds__(64)
void chunk_state(const bf16* __restrict__ k, const bf16* __restrict__ v,
                 const bf16* __restrict__ w,
                 _Float16* __restrict__ Sloc, float* __restrict__ D)
{
    int c = blockIdx.x, bh = blockIdx.y;
    int b = bh >> 4, h = bh & 15;
    int lane = threadIdx.x;            // k index
    __shared__ __align__(16) float sh[2][64];
    size_t base = (size_t)b * 2048 * 1024 + (size_t)h * 64 + (size_t)c * 32 * 1024;

    float S[64];
#pragma unroll
    for (int i = 0; i < 64; ++i) S[i] = 0.f;
    float Dl = 1.f;

    const unsigned short* kp = (const unsigned short*)k;
    const unsigned short* vp = (const unsigned short*)v;
    const unsigned short* wp = (const unsigned short*)w;
    unsigned short kr[4], vr[4], wr[4];
#pragma unroll
    for (int j = 0; j < 4; ++j) {
        size_t a = base + (size_t)j * 1024 + lane;
        kr[j] = kp[a]; vr[j] = vp[a]; wr[j] = wp[a];
    }
    for (int t = 0; t < 32; ++t) {
        int slot = t & 3, p = t & 1;
        float kl = bf2f(kr[slot]);
        float vl = bf2f(vr[slot]);
        float wl = bf2f(wr[slot]);
        if (t + 4 < 32) {
            size_t a = base + (size_t)(t + 4) * 1024 + lane;
            kr[slot] = kp[a]; vr[slot] = vp[a]; wr[slot] = wp[a];
        }
        float el = __expf(-wl);
        float kb = kl * (1.f - el);
        Dl *= el;
        sh[p][lane] = vl;
        __syncthreads();
        const float4* v4 = (const float4*)sh[p];
#pragma unroll
        for (int vv = 0; vv < 16; ++vv) {
            float4 vx = v4[vv];
            int s = vv * 4;
            S[s + 0] = S[s + 0] * el + kb * vx.x;
            S[s + 1] = S[s + 1] * el + kb * vx.y;
            S[s + 2] = S[s + 2] * el + kb * vx.z;
            S[s + 3] = S[s + 3] * el + kb * vx.w;
        }
    }
    _Float16* So = Sloc + ((size_t)bh * 64 + c) * 4096;
#pragma unroll
    for (int i = 0; i < 64; ++i) So[(size_t)i * 64 + lane] = (_Float16)S[i];
    D[((size_t)bh * 64 + c) * 64 + lane] = Dl;
}

// Phase B: S0_{c+1} = S0_c*D_c + Sloc_c (exact, f32 accum); Sloc_c := S0_c.
// 16 independent chains per thread for ILP.
__global__ __launch_bounds__(256)
void chunk_combine(_Float16* __restrict__ Sloc, const float* __restrict__ D)
{
    int bh = blockIdx.x;
    int tid = threadIdx.x;
    int k = tid & 63, v0 = tid >> 6;
    float s[16];
#pragma unroll
    for (int j = 0; j < 16; ++j) s[j] = 0.f;
    for (int c = 0; c < 64; ++c) {
        float Dk = D[((size_t)bh * 64 + c) * 64 + k];
        size_t basei = ((size_t)bh * 64 + c) * 4096 + k;
#pragma unroll
        for (int j = 0; j < 16; ++j) {
            size_t idx = basei + (size_t)(v0 + j * 4) * 64;
            float tmp = (float)Sloc[idx];
            Sloc[idx] = (_Float16)s[j];
            s[j] = s[j] * Dk + tmp;
        }
    }
}

// Phase C: recurrence from S0_c with outputs, gate fused, gate buffer in-place.
__global__ __launch_bounds__(64)
void chunk_out(const bf16* __restrict__ q, const bf16* __restrict__ k,
               const bf16* __restrict__ v, const bf16* __restrict__ w,
               const bf16* gate, const _Float16* __restrict__ S0buf,
               bf16* ag)
{
    int c = blockIdx.x, bh = blockIdx.y;
    int b = bh >> 4, h = bh & 15;
    int lane = threadIdx.x;            // v index
    __shared__ __align__(16) float sh[2][3][64];
    size_t base = (size_t)b * 2048 * 1024 + (size_t)h * 64 + (size_t)c * 32 * 1024;

    float S[64];
    const h8* S0 = (const h8*)(S0buf + ((size_t)bh * 64 + c) * 4096 + (size_t)lane * 64);
#pragma unroll
    for (int i = 0; i < 8; ++i) {
        h8 hv = S0[i];
#pragma unroll
        for (int j = 0; j < 8; ++j) S[i * 8 + j] = (float)hv[j];
    }

    const unsigned short* qp = (const unsigned short*)q;
    const unsigned short* kp = (const unsigned short*)k;
    const unsigned short* vp = (const unsigned short*)v;
    const unsigned short* wp = (const unsigned short*)w;
    const unsigned short* gp = (const unsigned short*)gate;
    unsigned short qr[4], kr[4], vr[4], wr[4], gr[4];
#pragma unroll
    for (int j = 0; j < 4; ++j) {
        size_t a = base + (size_t)j * 1024 + lane;
        qr[j] = qp[a]; kr[j] = kp[a]; vr[j] = vp[a]; wr[j] = wp[a]; gr[j] = gp[a];
    }
    for (int t = 0; t < 32; ++t) {
        int slot = t & 3, p = t & 1;
        float ql = bf2f(qr[slot]) * 0.125f;
        float kl = bf2f(kr[slot]);
        float vl = bf2f(vr[slot]);
        float wl = bf2f(wr[slot]);
        float gl = bf2f(gr[slot]);
        if (t + 4 < 32) {
            size_t a = base + (size_t)(t + 4) * 1024 + lane;
            qr[slot] = qp[a]; kr[slot] = kp[a]; vr[slot] = vp[a];
            wr[slot] = wp[a]; gr[slot] = gp[a];
        }
        float el = __expf(-wl);
        sh[p][0][lane] = ql;
        sh[p][1][lane] = kl * (1.f - el);
        sh[p][2][lane] = el;
        __syncthreads();
        const float4* q4 = (const float4*)sh[p][0];
        const float4* k4 = (const float4*)sh[p][1];
        const float4* e4 = (const float4*)sh[p][2];
        float a0 = 0.f, a1 = 0.f, a2 = 0.f, a3 = 0.f;
#pragma unroll
        for (int kk = 0; kk < 16; ++kk) {
            float4 qq = q4[kk], kx = k4[kk], ee = e4[kk];
            int s = kk * 4;
            S[s + 0] = S[s + 0] * ee.x + kx.x * vl; a0 += qq.x * S[s + 0];
            S[s + 1] = S[s + 1] * ee.y + kx.y * vl; a1 += qq.y * S[s + 1];
            S[s + 2] = S[s + 2] * ee.z + kx.z * vl; a2 += qq.z * S[s + 2];
            S[s + 3] = S[s + 3] * ee.w + kx.w * vl; a3 += qq.w * S[s + 3];
        }
        ag[base + (size_t)t * 1024 + lane] = __float2bfloat16(((a0 + a1) + (a2 + a3)) * gl);
    }
}

// ---------------- launch ----------------
extern "C" void kernel_launch(void* const* d_in, const int* in_sizes, int n_in,
                              void* d_out, int out_size, void* d_ws, size_t ws_size,
                              hipStream_t stream) {
    const float* x    = (const float*)d_in[0];
    const float* maax = (const float*)d_in[1];
    const float* maar = (const float*)d_in[2];
    const float* maak = (const float*)d_in[3];
    const float* maav = (const float*)d_in[4];
    const float* maaw = (const float*)d_in[5];
    const float* maag = (const float*)d_in[6];
    const float* w1   = (const float*)d_in[7];
    const float* w2   = (const float*)d_in[8];
    const float* td   = (const float*)d_in[9];
    const float* dw1  = (const float*)d_in[10];
    const float* dw2  = (const float*)d_in[11];
    const float* Wq   = (const float*)d_in[12];
    const float* Wk   = (const float*)d_in[13];
    const float* Wv   = (const float*)d_in[14];
    const float* Wo   = (const float*)d_in[15];
    const float* Wg   = (const float*)d_in[16];
    const float* bg   = (const float*)d_in[17];

    char* ws = (char*)d_ws;
    bf16*  xxx   = (bf16*) (ws + OFF_XXXQ);
    bf16*  qb    = (bf16*) (ws + OFF_XXXQ);
    bf16*  kb    = (bf16*) (ws + OFF_K);
    bf16*  vb    = (bf16*) (ws + OFF_V);
    bf16*  wb    = (bf16*) (ws + OFF_W);
    bf16*  gateb = (bf16*) (ws + OFF_GATE);   // overwrites wqt/wkt/mp; consumed in-place -> ag
    bf16*  wqt   = (bf16*) (ws + OFF_WQT);
    bf16*  wkt   = (bf16*) (ws + OFF_WKT);
    float* mp    = (float*)(ws + OFF_MP);
    bf16*  xs0   = (bf16*) (ws + OFF_XS0);
    bf16*  xs1   = (bf16*) (ws + OFF_XS1);
    bf16*  wvt   = (bf16*) (ws + OFF_WVT);
    bf16*  wgt   = (bf16*) (ws + OFF_WGT);
    bf16*  wot   = (bf16*) (ws + OFF_WOT);
    bf16*  w1t   = (bf16*) (ws + OFF_W1T);
    bf16*  wd1t  = (bf16*) (ws + OFF_WD1T);
    bf16*  wd2t  = (bf16*) (ws + OFF_WD2T);
    bf16*  dect  = (bf16*) (ws + OFF_DECT);
    _Float16* Sloc = (_Float16*)(ws + OFF_SLOC);  // overlays dead xs0/xs1
    float* Dbuf  = (float*)(ws + OFF_D);          // overlays dead w1t

    transpose_all<<<5568, dim3(32, 8), 0, stream>>>(Wq, Wk, Wv, Wg, Wo, w1, dw1, dw2,
                                                    wqt, wkt, wvt, wgt, wot, w1t, wd1t, wd2t);
    prep_xxx<<<16384, 256, 0, stream>>>(x, maax, xxx);

    // mp = tanh(xxx @ W1)
    gemm_bt<1><<<dim3(32, 2), 256, 0, stream>>>(xxx, 1024, w1t, 1024, mp, 256, 1024, nullptr);

    // decay chain: xw -> dect -> wb = exp(decay)
    mix_stream<<<dim3(4, 1024), 256, 0, stream>>>(mp, w2, x, maaw, 3, xs0);
    gemm_bt<2><<<dim3(32, 1), 256, 0, stream>>>(xs0, 1024, wd1t, 1024, dect, 128, 1024, nullptr);
    gemm_bt<3><<<dim3(32, 8), 256, 0, stream>>>(dect, 128, wd2t, 64, wb, 1024, 64, td);

    // streams r,k -> q,k (batched)
    mix_stream2<<<dim3(4, 1024), 256, 0, stream>>>(mp, w2, x, maar, maak, 0, 1, xs0, xs1);
    gemm_bt2<5><<<dim3(32, 8, 2), 256, 0, stream>>>(xs0, xs1, 1024, wqt, wkt, 1024,
                                                    qb, kb, 1024, 1024, nullptr);

    // streams v,g -> v,gate (batched; gate overwrites dead wqt/wkt/mp)
    mix_stream2<<<dim3(4, 1024), 256, 0, stream>>>(mp, w2, x, maav, maag, 2, 4, xs0, xs1);
    gemm_bt2<4><<<dim3(32, 8, 2), 256, 0, stream>>>(xs0, xs1, 1024, wvt, wgt, 1024,
                                                    vb, gateb, 1024, 1024, bg);

    // chunked scan: NC=64, L=32
    chunk_state  <<<dim3(64, 32),  64, 0, stream>>>(kb, vb, wb, Sloc, Dbuf);
    chunk_combine<<<32,           256, 0, stream>>>(Sloc, Dbuf);
    chunk_out    <<<dim3(64, 32),  64, 0, stream>>>(qb, kb, vb, wb, gateb, Sloc, gateb);

    // out = (o*gate) @ Wo -> f32
    gemm_bt<6><<<dim3(32, 8), 256, 0, stream>>>(gateb, 1024, wot, 1024, (float*)d_out, 1024, 1024, nullptr);

    (void)in_sizes; (void)n_in; (void)out_size; (void)ws_size;
}